// Round 4
// baseline (514.078 us; speedup 1.0000x reference)
//
#include <hip/hip_runtime.h>
#include <math.h>

typedef __bf16 bf16x8 __attribute__((ext_vector_type(8)));
typedef float f32x4 __attribute__((ext_vector_type(4)));
typedef float f32x2 __attribute__((ext_vector_type(2)));

#define NVIEWS 4
#define RESN 64
#define PP 4096
#define FEATC 32
#define PRES 256
#define NSAMP 92
#define STEPF ((2.7f - 1.0f) / 92.0f)
#define FOVF 0.8575560548920328f

#define RPB 8                 // rays per block
#define SB (RPB * NSAMP)      // 736 samples per block
#define TPB 512               // 8 waves
#define CH 256                // samples per chunk
#define NCHUNK 3
#define HPAD 72               // hbuf row stride (bf16), 144B: mult of 16 -> aligned b128

// -------- transpose planes (v,pl,c,y,x) -> (v,pl,y,x,c) --------
__global__ __launch_bounds__(PRES) void transpose_planes(
    const float* __restrict__ in, float* __restrict__ out) {
  int b  = blockIdx.x;          // vp*256 + y
  int vp = b >> 8;
  int y  = b & 255;
  int x  = threadIdx.x;
  const float* src = in + (size_t)vp * FEATC * PRES * PRES + (size_t)y * PRES + x;
  float* dst = out + (((size_t)vp * PRES + y) * PRES + x) * FEATC;
  float v[FEATC];
#pragma unroll
  for (int c = 0; c < FEATC; ++c) v[c] = src[(size_t)c * PRES * PRES];
#pragma unroll
  for (int q = 0; q < FEATC / 4; ++q) {
    float4 t = make_float4(v[q * 4 + 0], v[q * 4 + 1], v[q * 4 + 2], v[q * 4 + 3]);
    *reinterpret_cast<float4*>(dst + q * 4) = t;
  }
}

__device__ __forceinline__ unsigned short f2bf(float x) {
  unsigned int u = __float_as_uint(x);
  u += 0x7fffu + ((u >> 16) & 1u);
  return (unsigned short)(u >> 16);
}
__device__ __forceinline__ f32x2 mk2(float a, float b) { f32x2 r; r[0] = a; r[1] = b; return r; }

// -------- fused MFMA render --------
template <int TR>
__global__ __launch_bounds__(TPB, 4) void render_mfma(
    const float* __restrict__ c2w, const float* __restrict__ planes,
    const float* __restrict__ background, const float* __restrict__ t_jitter,
    const float* __restrict__ W1, const float* __restrict__ b1,
    const float* __restrict__ W2, const float* __restrict__ b2,
    const float* __restrict__ Wr1, const float* __restrict__ br1,
    const float* __restrict__ Wr2, const float* __restrict__ br2,
    float* __restrict__ out) {
  __shared__ __bf16 hbuf[CH][HPAD];   // feat(0-31) -> h(0-63) -> colorA(0-31) -> hr(0-63)
  __shared__ float alphaL[SB];        // raw o0, then alpha after dense phase
  __shared__ float rgbL[SB * 3];      // raw logits, then sigmoid after dense phase
  __shared__ uint2 dirS[CH];          // packed bf16 dir per sample row

  const int tid = threadIdx.x;
  const int w = tid >> 6;
  const int lane = tid & 63;
  const int lr = lane & 15;
  const int lg = lane >> 4;

  // ---- weight fragments: direct per-lane global loads (L1-broadcast) ----
  // B-frag layout (16x16x32): col n = lane&15, k = (lane>>4)*8 + i
  bf16x8 fW1[3][4], fW2[2], fR1[4], fR2[2];
#pragma unroll
  for (int ks = 0; ks < 3; ++ks)
#pragma unroll
    for (int nt = 0; nt < 4; ++nt) {
      union { unsigned short u[8]; bf16x8 b; } t;
#pragma unroll
      for (int i = 0; i < 8; ++i)
        t.u[i] = f2bf(W1[(ks * 32 + lg * 8 + i) * 64 + nt * 16 + lr]);
      fW1[ks][nt] = t.b;
    }
#pragma unroll
  for (int ks = 0; ks < 2; ++ks) {
    union { unsigned short u[8]; bf16x8 b; } t;
#pragma unroll
    for (int i = 0; i < 8; ++i)
      t.u[i] = f2bf(W2[(ks * 32 + lg * 8 + i) * 16 + lr]);
    fW2[ks] = t.b;
  }
#pragma unroll
  for (int nt = 0; nt < 4; ++nt) {
    union { unsigned short u[8]; bf16x8 b; } t;
#pragma unroll
    for (int i = 0; i < 8; ++i) {
      const int k = lg * 8 + i;
      t.u[i] = (k < 18) ? f2bf(Wr1[k * 64 + nt * 16 + lr]) : (unsigned short)0;
    }
    fR1[nt] = t.b;
  }
#pragma unroll
  for (int ks = 0; ks < 2; ++ks) {
    union { unsigned short u[8]; bf16x8 b; } t;
#pragma unroll
    for (int i = 0; i < 8; ++i)
      t.u[i] = (lr < 3) ? f2bf(Wr2[(ks * 32 + lg * 8 + i) * 3 + lr]) : (unsigned short)0;
    fR2[ks] = t.b;
  }
  float b1v[4], br1v[4];
#pragma unroll
  for (int nt = 0; nt < 4; ++nt) { b1v[nt] = b1[nt * 16 + lr]; br1v[nt] = br1[nt * 16 + lr]; }
  const float b2v = b2[lr];
  const float br2v = (lr < 3) ? br2[lr] : 0.f;

  const float foc = 0.5f * (float)RESN / tanf(FOVF * 0.5f);

  for (int chunk = 0; chunk < NCHUNK; ++chunk) {
    __syncthreads();   // prev chunk's GEMM4 hbuf reads + GEMM2-epi dirS reads done
    // ---- setup: 2 threads per sample ----
    const int mc = tid >> 1;
    const int half = tid & 1;
    const int sb = chunk * CH + mc;
    const bool valid = sb < SB;
    float px = 0, py = 0, pz = 0;
    int view = 0;
    if (valid) {
      const int rb = sb / NSAMP;
      const int s = sb - rb * NSAMP;
      const int ray = blockIdx.x * RPB + rb;
      view = ray >> 12;
      const int p = ray & 4095;
      const float dx = ((float)(p & 63) + 0.5f - 32.f) / foc;
      const float dy = ((float)(p >> 6) + 0.5f - 32.f) / foc;
      const float* M = c2w + view * 16;
      const float rdx = M[0] * dx + M[1] * dy + M[2];
      const float rdy = M[4] * dx + M[5] * dy + M[6];
      const float rdz = M[8] * dx + M[9] * dy + M[10];
      const float jit = t_jitter[(size_t)ray * NSAMP + s];
      const float t = 1.0f + ((float)s + jit) * STEPF + STEPF * 0.5f;
      px = fminf(fmaxf(M[3] + 0.5f + rdx * t, 0.f), 1.f);
      py = fminf(fmaxf(M[7] + 0.5f + rdy * t, 0.f), 1.f);
      pz = fminf(fmaxf(M[11] + 0.5f + rdz * t, 0.f), 1.f);
      if (half == 0) {
        uint2 d;
        d.x = (unsigned int)f2bf(rdx) | ((unsigned int)f2bf(rdy) << 16);
        d.y = (unsigned int)f2bf(rdz);
        dirS[mc] = d;
      }
    }

    // ---- GEMM1: feat[256x96] @ W1, K streamed per plane ----
    f32x4 acc1[2][4] = {};
#pragma unroll
    for (int pl = 0; pl < 3; ++pl) {
      if (pl) __syncthreads();           // prev plane A-reads done
      if (valid) {
        const float uu = (pl == 2) ? py : px;
        const float vv = (pl == 0) ? py : pz;
        const float xf = uu * 255.f, yf = vv * 255.f;
        const float x0f = floorf(xf), y0f = floorf(yf);
        const float wx = xf - x0f, wy = yf - y0f;
        const int x0 = (int)x0f, y0 = (int)y0f;
        const int x1 = min(x0 + 1, 255), y1 = min(y0 + 1, 255);
        const float w00 = (1.f - wx) * (1.f - wy), w01 = wx * (1.f - wy);
        const float w10 = (1.f - wx) * wy, w11 = wx * wy;
        bf16x8 v0, v1;
        if (TR) {
          const float* pb = planes + (size_t)(view * 3 + pl) * (PRES * PRES * FEATC) + half * 16;
          const float* p00 = pb + (size_t)(y0 * 256 + x0) * 32;
          const float* p01 = pb + (size_t)(y0 * 256 + x1) * 32;
          const float* p10 = pb + (size_t)(y1 * 256 + x0) * 32;
          const float* p11 = pb + (size_t)(y1 * 256 + x1) * 32;
          f32x2 fp[8];
#pragma unroll
          for (int q = 0; q < 4; ++q) {
            const float4 a = *(const float4*)(p00 + q * 4);
            const float4 b = *(const float4*)(p01 + q * 4);
            const float4 c = *(const float4*)(p10 + q * 4);
            const float4 d = *(const float4*)(p11 + q * 4);
            fp[q * 2 + 0] = mk2(a.x, a.y) * w00 + mk2(b.x, b.y) * w01 +
                            mk2(c.x, c.y) * w10 + mk2(d.x, d.y) * w11;
            fp[q * 2 + 1] = mk2(a.z, a.w) * w00 + mk2(b.z, b.w) * w01 +
                            mk2(c.z, c.w) * w10 + mk2(d.z, d.w) * w11;
          }
#pragma unroll
          for (int i = 0; i < 4; ++i) {
            v0[2 * i] = (__bf16)fp[i][0];       v0[2 * i + 1] = (__bf16)fp[i][1];
            v1[2 * i] = (__bf16)fp[4 + i][0];   v1[2 * i + 1] = (__bf16)fp[4 + i][1];
          }
        } else {
          const float* pb = planes + (size_t)(view * 3 + pl) * (FEATC * PRES * PRES) +
                            (size_t)(half * 16) * (PRES * PRES);
          const int o00 = y0 * 256 + x0, o01 = y0 * 256 + x1;
          const int o10 = y1 * 256 + x0, o11 = y1 * 256 + x1;
          float f[16];
#pragma unroll
          for (int cc = 0; cc < 16; ++cc) {
            const float* pc = pb + (size_t)cc * (PRES * PRES);
            f[cc] = pc[o00] * w00 + pc[o01] * w01 + pc[o10] * w10 + pc[o11] * w11;
          }
#pragma unroll
          for (int i = 0; i < 8; ++i) { v0[i] = (__bf16)f[i]; v1[i] = (__bf16)f[8 + i]; }
        }
        *(bf16x8*)&hbuf[mc][half * 16] = v0;
        *(bf16x8*)&hbuf[mc][half * 16 + 8] = v1;
      }
      __syncthreads();
#pragma unroll
      for (int mt = 0; mt < 2; ++mt) {
        const int m = (2 * w + mt) * 16 + lr;
        const bf16x8 a = *(const bf16x8*)&hbuf[m][lg * 8];
#pragma unroll
        for (int nt = 0; nt < 4; ++nt)
          acc1[mt][nt] = __builtin_amdgcn_mfma_f32_16x16x32_bf16(a, fW1[pl][nt], acc1[mt][nt], 0, 0, 0);
      }
    }
    __syncthreads();
    // h = relu(acc1 + b1) -> hbuf cols 0..63
#pragma unroll
    for (int mt = 0; mt < 2; ++mt)
#pragma unroll
      for (int nt = 0; nt < 4; ++nt)
#pragma unroll
        for (int r = 0; r < 4; ++r) {
          const int m = (2 * w + mt) * 16 + lg * 4 + r;
          hbuf[m][nt * 16 + lr] = (__bf16)fmaxf(acc1[mt][nt][r] + b1v[nt], 0.f);
        }
    __syncthreads();
    // ---- GEMM2: h @ W2 (64->16) ----
    f32x4 acc2[2] = {};
#pragma unroll
    for (int mt = 0; mt < 2; ++mt) {
      const int m = (2 * w + mt) * 16 + lr;
      const bf16x8 a0 = *(const bf16x8*)&hbuf[m][lg * 8];
      const bf16x8 a1 = *(const bf16x8*)&hbuf[m][32 + lg * 8];
      acc2[mt] = __builtin_amdgcn_mfma_f32_16x16x32_bf16(a0, fW2[0], acc2[mt], 0, 0, 0);
      acc2[mt] = __builtin_amdgcn_mfma_f32_16x16x32_bf16(a1, fW2[1], acc2[mt], 0, 0, 0);
    }
    __syncthreads();   // GEMM2 reads done; cols 0..17 now rewritable
    // epilogue: raw sigma -> alphaL; geo -> cols 3..17; dir -> cols 0..2
#pragma unroll
    for (int mt = 0; mt < 2; ++mt)
#pragma unroll
      for (int r = 0; r < 4; ++r) {
        const int m = (2 * w + mt) * 16 + lg * 4 + r;
        const int sb2 = chunk * CH + m;
        const float val = acc2[mt][r] + b2v;
        if (lr == 0) {
          if (sb2 < SB) alphaL[sb2] = val;
          const uint2 d = dirS[m];
          *(unsigned int*)&hbuf[m][0] = d.x;
          *(unsigned short*)&hbuf[m][2] = (unsigned short)d.y;
        } else {
          hbuf[m][2 + lr] = (__bf16)val;   // geo i=lr-1 -> col 3+(lr-1)
        }
      }
    __syncthreads();
    // ---- GEMM3: colorA[256x32] @ Wr1pad (cols 18..31 garbage x zero weights) ----
    f32x4 acc3[2][4] = {};
#pragma unroll
    for (int mt = 0; mt < 2; ++mt) {
      const int m = (2 * w + mt) * 16 + lr;
      const bf16x8 a = *(const bf16x8*)&hbuf[m][lg * 8];
#pragma unroll
      for (int nt = 0; nt < 4; ++nt)
        acc3[mt][nt] = __builtin_amdgcn_mfma_f32_16x16x32_bf16(a, fR1[nt], acc3[mt][nt], 0, 0, 0);
    }
    __syncthreads();   // GEMM3 A-reads done before hr overwrites cols 0..31
#pragma unroll
    for (int mt = 0; mt < 2; ++mt)
#pragma unroll
      for (int nt = 0; nt < 4; ++nt)
#pragma unroll
        for (int r = 0; r < 4; ++r) {
          const int m = (2 * w + mt) * 16 + lg * 4 + r;
          hbuf[m][nt * 16 + lr] = (__bf16)fmaxf(acc3[mt][nt][r] + br1v[nt], 0.f);
        }
    __syncthreads();
    // ---- GEMM4: hr @ Wr2pad -> raw rgb logits ----
    f32x4 acc4[2] = {};
#pragma unroll
    for (int mt = 0; mt < 2; ++mt) {
      const int m = (2 * w + mt) * 16 + lr;
      const bf16x8 a0 = *(const bf16x8*)&hbuf[m][lg * 8];
      const bf16x8 a1 = *(const bf16x8*)&hbuf[m][32 + lg * 8];
      acc4[mt] = __builtin_amdgcn_mfma_f32_16x16x32_bf16(a0, fR2[0], acc4[mt], 0, 0, 0);
      acc4[mt] = __builtin_amdgcn_mfma_f32_16x16x32_bf16(a1, fR2[1], acc4[mt], 0, 0, 0);
    }
#pragma unroll
    for (int mt = 0; mt < 2; ++mt)
#pragma unroll
      for (int r = 0; r < 4; ++r) {
        const int m = (2 * w + mt) * 16 + lg * 4 + r;
        const int sb2 = chunk * CH + m;
        if (lr < 3 && sb2 < SB) rgbL[sb2 * 3 + lr] = acc4[mt][r] + br2v;
      }
  }

  __syncthreads();
  // ---- dense activation phases ----
  for (int i = tid; i < SB; i += TPB) {
    const float v = alphaL[i];
    const float sp = fmaxf(v, 0.f) + log1pf(__expf(-fabsf(v)));
    alphaL[i] = 1.f - __expf(-sp * STEPF);
  }
  for (int i = tid; i < SB * 3; i += TPB) {
    const float x = rgbL[i];
    rgbL[i] = 1.f / (1.f + __expf(-x));
  }
  __syncthreads();

  // ---- wave-parallel composite: wave w -> ray w ----
  {
    const int ray = blockIdx.x * RPB + w;
    const int vw = ray >> 12;
    const int base = w * NSAMP;
    // phase A: samples 0..63
    const float a = alphaL[base + lane];
    float q = 1.f - a + 1e-10f;
#pragma unroll
    for (int d = 1; d < 64; d <<= 1) { const float t = __shfl_up(q, d); if (lane >= d) q *= t; }
    float T = __shfl_up(q, 1);
    if (lane == 0) T = 1.f;
    const float wgt = T * a;
    float cr = wgt * rgbL[(base + lane) * 3 + 0];
    float cg = wgt * rgbL[(base + lane) * 3 + 1];
    float cb = wgt * rgbL[(base + lane) * 3 + 2];
    float accA = wgt;
    const float Ttot = __shfl(q, 63);
    // phase B: samples 64..91 on lanes 0..27
    const int i2 = base + 64 + lane;
    const float a2 = (lane < 28) ? alphaL[i2] : 0.f;
    float q2 = 1.f - a2 + 1e-10f;
#pragma unroll
    for (int d = 1; d < 64; d <<= 1) { const float t = __shfl_up(q2, d); if (lane >= d) q2 *= t; }
    float T2 = __shfl_up(q2, 1);
    if (lane == 0) T2 = 1.f;
    T2 *= Ttot;
    if (lane < 28) {
      const float w2 = T2 * a2;
      cr += w2 * rgbL[i2 * 3 + 0];
      cg += w2 * rgbL[i2 * 3 + 1];
      cb += w2 * rgbL[i2 * 3 + 2];
      accA += w2;
    }
#pragma unroll
    for (int d = 32; d; d >>= 1) {
      cr += __shfl_xor(cr, d); cg += __shfl_xor(cg, d);
      cb += __shfl_xor(cb, d); accA += __shfl_xor(accA, d);
    }
    if (lane == 0) {
      const float* bg = background + vw * 3;
      float* po = out + (size_t)ray * 3;
      po[0] = cr + (1.f - accA) * bg[0];
      po[1] = cg + (1.f - accA) * bg[1];
      po[2] = cb + (1.f - accA) * bg[2];
    }
  }
}

extern "C" void kernel_launch(void* const* d_in, const int* in_sizes, int n_in,
                              void* d_out, int out_size, void* d_ws, size_t ws_size,
                              hipStream_t stream) {
  const float* c2w        = (const float*)d_in[0];
  const float* planes     = (const float*)d_in[1];
  const float* background = (const float*)d_in[2];
  const float* t_jitter   = (const float*)d_in[3];
  const float* W1  = (const float*)d_in[4];
  const float* b1  = (const float*)d_in[5];
  const float* W2  = (const float*)d_in[6];
  const float* b2  = (const float*)d_in[7];
  const float* Wr1 = (const float*)d_in[8];
  const float* br1 = (const float*)d_in[9];
  const float* Wr2 = (const float*)d_in[10];
  const float* br2 = (const float*)d_in[11];
  float* out = (float*)d_out;

  const int n_blocks = NVIEWS * PP / RPB;  // 2048
  const size_t tr_bytes = (size_t)NVIEWS * 3 * PRES * PRES * FEATC * sizeof(float);

  if (ws_size >= tr_bytes) {
    float* tp = (float*)d_ws;
    transpose_planes<<<NVIEWS * 3 * PRES, PRES, 0, stream>>>(planes, tp);
    render_mfma<1><<<n_blocks, TPB, 0, stream>>>(
        c2w, tp, background, t_jitter, W1, b1, W2, b2, Wr1, br1, Wr2, br2, out);
  } else {
    render_mfma<0><<<n_blocks, TPB, 0, stream>>>(
        c2w, planes, background, t_jitter, W1, b1, W2, b2, Wr1, br1, Wr2, br2, out);
  }
}

// Round 5
// 424.713 us; speedup vs baseline: 1.2104x; 1.2104x over previous
//
#include <hip/hip_runtime.h>
#include <math.h>

typedef __bf16 bf16x8 __attribute__((ext_vector_type(8)));
typedef float f32x4 __attribute__((ext_vector_type(4)));
typedef float f32x2 __attribute__((ext_vector_type(2)));

#define NVIEWS 4
#define RESN 64
#define PP 4096
#define FEATC 32
#define PRES 256
#define NSAMP 92
#define STEPF ((2.7f - 1.0f) / 92.0f)
#define FOVF 0.8575560548920328f

#define RPB 8                 // rays per block
#define SB (RPB * NSAMP)      // 736 samples per block
#define TPB 256               // 4 waves
#define CH 128                // samples per chunk (8 M-tiles; wave w owns tiles 2w,2w+1)
#define NCHUNK 6              // ceil(736/128)
#define HPAD 72               // hbuf row stride (bf16), 144B: mult of 16 -> aligned b128

// -------- transpose planes (v,pl,c,y,x) -> (v,pl,y,x,c) --------
__global__ __launch_bounds__(PRES) void transpose_planes(
    const float* __restrict__ in, float* __restrict__ out) {
  int b  = blockIdx.x;          // vp*256 + y
  int vp = b >> 8;
  int y  = b & 255;
  int x  = threadIdx.x;
  const float* src = in + (size_t)vp * FEATC * PRES * PRES + (size_t)y * PRES + x;
  float* dst = out + (((size_t)vp * PRES + y) * PRES + x) * FEATC;
  float v[FEATC];
#pragma unroll
  for (int c = 0; c < FEATC; ++c) v[c] = src[(size_t)c * PRES * PRES];
#pragma unroll
  for (int q = 0; q < FEATC / 4; ++q) {
    float4 t = make_float4(v[q * 4 + 0], v[q * 4 + 1], v[q * 4 + 2], v[q * 4 + 3]);
    *reinterpret_cast<float4*>(dst + q * 4) = t;
  }
}

__device__ __forceinline__ unsigned short f2bf(float x) {
  unsigned int u = __float_as_uint(x);
  u += 0x7fffu + ((u >> 16) & 1u);
  return (unsigned short)(u >> 16);
}
__device__ __forceinline__ f32x2 mk2(float a, float b) { f32x2 r; r[0] = a; r[1] = b; return r; }

// -------- fused MFMA render --------
// 256 threads / 4 waves; per-wave register shape mirrors the round-2 kernel
// (2 M-tiles + full weight-fragment set = ~112 VGPR) which fits the 128-VGPR
// cap implied by __launch_bounds__(256,4) -> 4 blocks/CU.
template <int TR>
__global__ __launch_bounds__(TPB, 4) void render_mfma(
    const float* __restrict__ c2w, const float* __restrict__ planes,
    const float* __restrict__ background, const float* __restrict__ t_jitter,
    const float* __restrict__ W1, const float* __restrict__ b1,
    const float* __restrict__ W2, const float* __restrict__ b2,
    const float* __restrict__ Wr1, const float* __restrict__ br1,
    const float* __restrict__ Wr2, const float* __restrict__ br2,
    float* __restrict__ out) {
  __shared__ __bf16 hbuf[CH][HPAD];   // feat(0-31) -> h(0-63) -> colorA(0-31) -> hr(0-63)
  __shared__ float alphaL[SB];        // raw o0, then alpha after dense phase
  __shared__ float rgbL[SB * 3];      // raw logits, then sigmoid after dense phase
  __shared__ uint2 dirS[CH];          // packed bf16 dir per sample row

  const int tid = threadIdx.x;
  const int w = tid >> 6;        // wave 0..3
  const int lane = tid & 63;
  const int lr = lane & 15;
  const int lg = lane >> 4;

  // ---- weight fragments: direct per-lane global loads (L1-broadcast) ----
  // B-frag layout (16x16x32): col n = lane&15, k = (lane>>4)*8 + i
  bf16x8 fW1[3][4], fW2[2], fR1[4], fR2[2];
#pragma unroll
  for (int ks = 0; ks < 3; ++ks)
#pragma unroll
    for (int nt = 0; nt < 4; ++nt) {
      union { unsigned short u[8]; bf16x8 b; } t;
#pragma unroll
      for (int i = 0; i < 8; ++i)
        t.u[i] = f2bf(W1[(ks * 32 + lg * 8 + i) * 64 + nt * 16 + lr]);
      fW1[ks][nt] = t.b;
    }
#pragma unroll
  for (int ks = 0; ks < 2; ++ks) {
    union { unsigned short u[8]; bf16x8 b; } t;
#pragma unroll
    for (int i = 0; i < 8; ++i)
      t.u[i] = f2bf(W2[(ks * 32 + lg * 8 + i) * 16 + lr]);
    fW2[ks] = t.b;
  }
#pragma unroll
  for (int nt = 0; nt < 4; ++nt) {
    union { unsigned short u[8]; bf16x8 b; } t;
#pragma unroll
    for (int i = 0; i < 8; ++i) {
      const int k = lg * 8 + i;
      t.u[i] = (k < 18) ? f2bf(Wr1[k * 64 + nt * 16 + lr]) : (unsigned short)0;
    }
    fR1[nt] = t.b;
  }
#pragma unroll
  for (int ks = 0; ks < 2; ++ks) {
    union { unsigned short u[8]; bf16x8 b; } t;
#pragma unroll
    for (int i = 0; i < 8; ++i)
      t.u[i] = (lr < 3) ? f2bf(Wr2[(ks * 32 + lg * 8 + i) * 3 + lr]) : (unsigned short)0;
    fR2[ks] = t.b;
  }
  float b1v[4], br1v[4];
#pragma unroll
  for (int nt = 0; nt < 4; ++nt) { b1v[nt] = b1[nt * 16 + lr]; br1v[nt] = br1[nt * 16 + lr]; }
  const float b2v = b2[lr];
  const float br2v = (lr < 3) ? br2[lr] : 0.f;

  const float foc = 0.5f * (float)RESN / tanf(FOVF * 0.5f);

  for (int chunk = 0; chunk < NCHUNK; ++chunk) {
    __syncthreads();   // prev chunk's GEMM4 hbuf reads + GEMM2-epi dirS reads done
    // ---- setup: 2 threads per sample (128 rows, 256 threads) ----
    const int mc = tid >> 1;
    const int half = tid & 1;
    const int sb = chunk * CH + mc;
    const bool valid = sb < SB;
    float px = 0, py = 0, pz = 0;
    int view = 0;
    if (valid) {
      const int rb = sb / NSAMP;
      const int s = sb - rb * NSAMP;
      const int ray = blockIdx.x * RPB + rb;
      view = ray >> 12;
      const int p = ray & 4095;
      const float dx = ((float)(p & 63) + 0.5f - 32.f) / foc;
      const float dy = ((float)(p >> 6) + 0.5f - 32.f) / foc;
      const float* M = c2w + view * 16;
      const float rdx = M[0] * dx + M[1] * dy + M[2];
      const float rdy = M[4] * dx + M[5] * dy + M[6];
      const float rdz = M[8] * dx + M[9] * dy + M[10];
      const float jit = t_jitter[(size_t)ray * NSAMP + s];
      const float t = 1.0f + ((float)s + jit) * STEPF + STEPF * 0.5f;
      px = fminf(fmaxf(M[3] + 0.5f + rdx * t, 0.f), 1.f);
      py = fminf(fmaxf(M[7] + 0.5f + rdy * t, 0.f), 1.f);
      pz = fminf(fmaxf(M[11] + 0.5f + rdz * t, 0.f), 1.f);
      if (half == 0) {
        uint2 d;
        d.x = (unsigned int)f2bf(rdx) | ((unsigned int)f2bf(rdy) << 16);
        d.y = (unsigned int)f2bf(rdz);
        dirS[mc] = d;
      }
    }

    // ---- GEMM1: feat[128x96] @ W1, K streamed per plane ----
    f32x4 acc1[2][4] = {};
#pragma unroll
    for (int pl = 0; pl < 3; ++pl) {
      if (pl) __syncthreads();           // prev plane A-reads done
      if (valid) {
        const float uu = (pl == 2) ? py : px;
        const float vv = (pl == 0) ? py : pz;
        const float xf = uu * 255.f, yf = vv * 255.f;
        const float x0f = floorf(xf), y0f = floorf(yf);
        const float wx = xf - x0f, wy = yf - y0f;
        const int x0 = (int)x0f, y0 = (int)y0f;
        const int x1 = min(x0 + 1, 255), y1 = min(y0 + 1, 255);
        const float w00 = (1.f - wx) * (1.f - wy), w01 = wx * (1.f - wy);
        const float w10 = (1.f - wx) * wy, w11 = wx * wy;
        bf16x8 v0, v1;
        if (TR) {
          const float* pb = planes + (size_t)(view * 3 + pl) * (PRES * PRES * FEATC) + half * 16;
          const float* p00 = pb + (size_t)(y0 * 256 + x0) * 32;
          const float* p01 = pb + (size_t)(y0 * 256 + x1) * 32;
          const float* p10 = pb + (size_t)(y1 * 256 + x0) * 32;
          const float* p11 = pb + (size_t)(y1 * 256 + x1) * 32;
          f32x2 fp[8];
#pragma unroll
          for (int q = 0; q < 4; ++q) {
            const float4 a = *(const float4*)(p00 + q * 4);
            const float4 b = *(const float4*)(p01 + q * 4);
            const float4 c = *(const float4*)(p10 + q * 4);
            const float4 d = *(const float4*)(p11 + q * 4);
            fp[q * 2 + 0] = mk2(a.x, a.y) * w00 + mk2(b.x, b.y) * w01 +
                            mk2(c.x, c.y) * w10 + mk2(d.x, d.y) * w11;
            fp[q * 2 + 1] = mk2(a.z, a.w) * w00 + mk2(b.z, b.w) * w01 +
                            mk2(c.z, c.w) * w10 + mk2(d.z, d.w) * w11;
          }
#pragma unroll
          for (int i = 0; i < 4; ++i) {
            v0[2 * i] = (__bf16)fp[i][0];       v0[2 * i + 1] = (__bf16)fp[i][1];
            v1[2 * i] = (__bf16)fp[4 + i][0];   v1[2 * i + 1] = (__bf16)fp[4 + i][1];
          }
        } else {
          const float* pb = planes + (size_t)(view * 3 + pl) * (FEATC * PRES * PRES) +
                            (size_t)(half * 16) * (PRES * PRES);
          const int o00 = y0 * 256 + x0, o01 = y0 * 256 + x1;
          const int o10 = y1 * 256 + x0, o11 = y1 * 256 + x1;
          float f[16];
#pragma unroll
          for (int cc = 0; cc < 16; ++cc) {
            const float* pc = pb + (size_t)cc * (PRES * PRES);
            f[cc] = pc[o00] * w00 + pc[o01] * w01 + pc[o10] * w10 + pc[o11] * w11;
          }
#pragma unroll
          for (int i = 0; i < 8; ++i) { v0[i] = (__bf16)f[i]; v1[i] = (__bf16)f[8 + i]; }
        }
        *(bf16x8*)&hbuf[mc][half * 16] = v0;
        *(bf16x8*)&hbuf[mc][half * 16 + 8] = v1;
      }
      __syncthreads();
#pragma unroll
      for (int mt = 0; mt < 2; ++mt) {
        const int m = (2 * w + mt) * 16 + lr;
        const bf16x8 a = *(const bf16x8*)&hbuf[m][lg * 8];
#pragma unroll
        for (int nt = 0; nt < 4; ++nt)
          acc1[mt][nt] = __builtin_amdgcn_mfma_f32_16x16x32_bf16(a, fW1[pl][nt], acc1[mt][nt], 0, 0, 0);
      }
    }
    __syncthreads();
    // h = relu(acc1 + b1) -> hbuf cols 0..63
#pragma unroll
    for (int mt = 0; mt < 2; ++mt)
#pragma unroll
      for (int nt = 0; nt < 4; ++nt)
#pragma unroll
        for (int r = 0; r < 4; ++r) {
          const int m = (2 * w + mt) * 16 + lg * 4 + r;
          hbuf[m][nt * 16 + lr] = (__bf16)fmaxf(acc1[mt][nt][r] + b1v[nt], 0.f);
        }
    __syncthreads();
    // ---- GEMM2: h @ W2 (64->16) ----
    f32x4 acc2[2] = {};
#pragma unroll
    for (int mt = 0; mt < 2; ++mt) {
      const int m = (2 * w + mt) * 16 + lr;
      const bf16x8 a0 = *(const bf16x8*)&hbuf[m][lg * 8];
      const bf16x8 a1 = *(const bf16x8*)&hbuf[m][32 + lg * 8];
      acc2[mt] = __builtin_amdgcn_mfma_f32_16x16x32_bf16(a0, fW2[0], acc2[mt], 0, 0, 0);
      acc2[mt] = __builtin_amdgcn_mfma_f32_16x16x32_bf16(a1, fW2[1], acc2[mt], 0, 0, 0);
    }
    __syncthreads();   // GEMM2 reads done; cols 0..17 now rewritable
    // epilogue: raw sigma -> alphaL; geo -> cols 3..17; dir -> cols 0..2
#pragma unroll
    for (int mt = 0; mt < 2; ++mt)
#pragma unroll
      for (int r = 0; r < 4; ++r) {
        const int m = (2 * w + mt) * 16 + lg * 4 + r;
        const int sb2 = chunk * CH + m;
        const float val = acc2[mt][r] + b2v;
        if (lr == 0) {
          if (sb2 < SB) alphaL[sb2] = val;
          const uint2 d = dirS[m];
          *(unsigned int*)&hbuf[m][0] = d.x;
          *(unsigned short*)&hbuf[m][2] = (unsigned short)d.y;
        } else {
          hbuf[m][2 + lr] = (__bf16)val;   // geo i=lr-1 -> col 3+(lr-1)
        }
      }
    __syncthreads();
    // ---- GEMM3: colorA[128x32] @ Wr1pad (cols 18..31 garbage x zero weights) ----
    f32x4 acc3[2][4] = {};
#pragma unroll
    for (int mt = 0; mt < 2; ++mt) {
      const int m = (2 * w + mt) * 16 + lr;
      const bf16x8 a = *(const bf16x8*)&hbuf[m][lg * 8];
#pragma unroll
      for (int nt = 0; nt < 4; ++nt)
        acc3[mt][nt] = __builtin_amdgcn_mfma_f32_16x16x32_bf16(a, fR1[nt], acc3[mt][nt], 0, 0, 0);
    }
    __syncthreads();   // GEMM3 A-reads done before hr overwrites cols 0..31
#pragma unroll
    for (int mt = 0; mt < 2; ++mt)
#pragma unroll
      for (int nt = 0; nt < 4; ++nt)
#pragma unroll
        for (int r = 0; r < 4; ++r) {
          const int m = (2 * w + mt) * 16 + lg * 4 + r;
          hbuf[m][nt * 16 + lr] = (__bf16)fmaxf(acc3[mt][nt][r] + br1v[nt], 0.f);
        }
    __syncthreads();
    // ---- GEMM4: hr @ Wr2pad -> raw rgb logits ----
    f32x4 acc4[2] = {};
#pragma unroll
    for (int mt = 0; mt < 2; ++mt) {
      const int m = (2 * w + mt) * 16 + lr;
      const bf16x8 a0 = *(const bf16x8*)&hbuf[m][lg * 8];
      const bf16x8 a1 = *(const bf16x8*)&hbuf[m][32 + lg * 8];
      acc4[mt] = __builtin_amdgcn_mfma_f32_16x16x32_bf16(a0, fR2[0], acc4[mt], 0, 0, 0);
      acc4[mt] = __builtin_amdgcn_mfma_f32_16x16x32_bf16(a1, fR2[1], acc4[mt], 0, 0, 0);
    }
#pragma unroll
    for (int mt = 0; mt < 2; ++mt)
#pragma unroll
      for (int r = 0; r < 4; ++r) {
        const int m = (2 * w + mt) * 16 + lg * 4 + r;
        const int sb2 = chunk * CH + m;
        if (lr < 3 && sb2 < SB) rgbL[sb2 * 3 + lr] = acc4[mt][r] + br2v;
      }
  }

  __syncthreads();
  // ---- dense activation phases ----
  for (int i = tid; i < SB; i += TPB) {
    const float v = alphaL[i];
    const float sp = fmaxf(v, 0.f) + log1pf(__expf(-fabsf(v)));
    alphaL[i] = 1.f - __expf(-sp * STEPF);
  }
  for (int i = tid; i < SB * 3; i += TPB) {
    const float x = rgbL[i];
    rgbL[i] = 1.f / (1.f + __expf(-x));
  }
  __syncthreads();

  // ---- wave-parallel composite: wave w -> rays w and w+4 ----
#pragma unroll
  for (int rr = 0; rr < 2; ++rr) {
    const int rloc = w + rr * 4;
    const int ray = blockIdx.x * RPB + rloc;
    const int vw = ray >> 12;
    const int base = rloc * NSAMP;
    // phase A: samples 0..63
    const float a = alphaL[base + lane];
    float q = 1.f - a + 1e-10f;
#pragma unroll
    for (int d = 1; d < 64; d <<= 1) { const float t = __shfl_up(q, d); if (lane >= d) q *= t; }
    float T = __shfl_up(q, 1);
    if (lane == 0) T = 1.f;
    const float wgt = T * a;
    float cr = wgt * rgbL[(base + lane) * 3 + 0];
    float cg = wgt * rgbL[(base + lane) * 3 + 1];
    float cb = wgt * rgbL[(base + lane) * 3 + 2];
    float accA = wgt;
    const float Ttot = __shfl(q, 63);
    // phase B: samples 64..91 on lanes 0..27
    const int i2 = base + 64 + lane;
    const float a2 = (lane < 28) ? alphaL[i2] : 0.f;
    float q2 = 1.f - a2 + 1e-10f;
#pragma unroll
    for (int d = 1; d < 64; d <<= 1) { const float t = __shfl_up(q2, d); if (lane >= d) q2 *= t; }
    float T2 = __shfl_up(q2, 1);
    if (lane == 0) T2 = 1.f;
    T2 *= Ttot;
    if (lane < 28) {
      const float w2 = T2 * a2;
      cr += w2 * rgbL[i2 * 3 + 0];
      cg += w2 * rgbL[i2 * 3 + 1];
      cb += w2 * rgbL[i2 * 3 + 2];
      accA += w2;
    }
#pragma unroll
    for (int d = 32; d; d >>= 1) {
      cr += __shfl_xor(cr, d); cg += __shfl_xor(cg, d);
      cb += __shfl_xor(cb, d); accA += __shfl_xor(accA, d);
    }
    if (lane == 0) {
      const float* bg = background + vw * 3;
      float* po = out + (size_t)ray * 3;
      po[0] = cr + (1.f - accA) * bg[0];
      po[1] = cg + (1.f - accA) * bg[1];
      po[2] = cb + (1.f - accA) * bg[2];
    }
  }
}

extern "C" void kernel_launch(void* const* d_in, const int* in_sizes, int n_in,
                              void* d_out, int out_size, void* d_ws, size_t ws_size,
                              hipStream_t stream) {
  const float* c2w        = (const float*)d_in[0];
  const float* planes     = (const float*)d_in[1];
  const float* background = (const float*)d_in[2];
  const float* t_jitter   = (const float*)d_in[3];
  const float* W1  = (const float*)d_in[4];
  const float* b1  = (const float*)d_in[5];
  const float* W2  = (const float*)d_in[6];
  const float* b2  = (const float*)d_in[7];
  const float* Wr1 = (const float*)d_in[8];
  const float* br1 = (const float*)d_in[9];
  const float* Wr2 = (const float*)d_in[10];
  const float* br2 = (const float*)d_in[11];
  float* out = (float*)d_out;

  const int n_blocks = NVIEWS * PP / RPB;  // 2048
  const size_t tr_bytes = (size_t)NVIEWS * 3 * PRES * PRES * FEATC * sizeof(float);

  if (ws_size >= tr_bytes) {
    float* tp = (float*)d_ws;
    transpose_planes<<<NVIEWS * 3 * PRES, PRES, 0, stream>>>(planes, tp);
    render_mfma<1><<<n_blocks, TPB, 0, stream>>>(
        c2w, tp, background, t_jitter, W1, b1, W2, b2, Wr1, br1, Wr2, br2, out);
  } else {
    render_mfma<0><<<n_blocks, TPB, 0, stream>>>(
        c2w, planes, background, t_jitter, W1, b1, W2, b2, Wr1, br1, Wr2, br2, out);
  }
}

// Round 6
// 234.080 us; speedup vs baseline: 2.1962x; 1.8144x over previous
//
#include <hip/hip_runtime.h>
#include <math.h>

typedef __bf16 bf16x8 __attribute__((ext_vector_type(8)));
typedef float f32x4 __attribute__((ext_vector_type(4)));
typedef float f32x2 __attribute__((ext_vector_type(2)));

#define NVIEWS 4
#define RESN 64
#define PP 4096
#define FEATC 32
#define PRES 256
#define NSAMP 92
#define STEPF ((2.7f - 1.0f) / 92.0f)
#define FOVF 0.8575560548920328f

#define RPB 8                 // rays per block
#define SB (RPB * NSAMP)      // 736 samples per block
#define TPB 256               // 4 waves
#define CH 128                // samples per chunk (8 M-tiles; wave w owns tiles 2w,2w+1)
#define NCHUNK 6              // ceil(736/128)
#define HPAD 72               // hbuf row stride (bf16), 144B: mult of 16 -> aligned b128

// -------- transpose planes (v,pl,c,y,x) -> (v,pl,y,x,c) --------
__global__ __launch_bounds__(PRES) void transpose_planes(
    const float* __restrict__ in, float* __restrict__ out) {
  int b  = blockIdx.x;          // vp*256 + y
  int vp = b >> 8;
  int y  = b & 255;
  int x  = threadIdx.x;
  const float* src = in + (size_t)vp * FEATC * PRES * PRES + (size_t)y * PRES + x;
  float* dst = out + (((size_t)vp * PRES + y) * PRES + x) * FEATC;
  float v[FEATC];
#pragma unroll
  for (int c = 0; c < FEATC; ++c) v[c] = src[(size_t)c * PRES * PRES];
#pragma unroll
  for (int q = 0; q < FEATC / 4; ++q) {
    float4 t = make_float4(v[q * 4 + 0], v[q * 4 + 1], v[q * 4 + 2], v[q * 4 + 3]);
    *reinterpret_cast<float4*>(dst + q * 4) = t;
  }
}

__device__ __forceinline__ unsigned short f2bf(float x) {
  unsigned int u = __float_as_uint(x);
  u += 0x7fffu + ((u >> 16) & 1u);
  return (unsigned short)(u >> 16);
}
__device__ __forceinline__ f32x2 mk2(float a, float b) { f32x2 r; r[0] = a; r[1] = b; return r; }

// -------- fused MFMA render --------
// 256 threads / 4 waves. __launch_bounds__(256,2): VGPR cap 256 -> no spill
// (live set ~112 arch VGPRs + MFMA accs); occupancy comes from the natural
// allocation (512/112 -> 4 waves/SIMD -> 4 blocks/CU with 31KB LDS).
// NOTE: (.,4) empirically forces a 64-VGPR cap on this toolchain -> ~1GB
// scratch spill traffic (rounds 4-5: FETCH_SIZE 631-696MB). Do not use.
template <int TR>
__global__ __launch_bounds__(TPB, 2) void render_mfma(
    const float* __restrict__ c2w, const float* __restrict__ planes,
    const float* __restrict__ background, const float* __restrict__ t_jitter,
    const float* __restrict__ W1, const float* __restrict__ b1,
    const float* __restrict__ W2, const float* __restrict__ b2,
    const float* __restrict__ Wr1, const float* __restrict__ br1,
    const float* __restrict__ Wr2, const float* __restrict__ br2,
    float* __restrict__ out) {
  __shared__ __bf16 hbuf[CH][HPAD];   // feat(0-31) -> h(0-63) -> colorA(0-31) -> hr(0-63)
  __shared__ float alphaL[SB];        // raw o0, then alpha after dense phase
  __shared__ float rgbL[SB * 3];      // raw logits, then sigmoid after dense phase
  __shared__ uint2 dirS[CH];          // packed bf16 dir per sample row

  const int tid = threadIdx.x;
  const int w = tid >> 6;        // wave 0..3
  const int lane = tid & 63;
  const int lr = lane & 15;
  const int lg = lane >> 4;

  // ---- weight fragments: direct per-lane global loads (L1-broadcast) ----
  // B-frag layout (16x16x32): col n = lane&15, k = (lane>>4)*8 + i
  bf16x8 fW1[3][4], fW2[2], fR1[4], fR2[2];
#pragma unroll
  for (int ks = 0; ks < 3; ++ks)
#pragma unroll
    for (int nt = 0; nt < 4; ++nt) {
      union { unsigned short u[8]; bf16x8 b; } t;
#pragma unroll
      for (int i = 0; i < 8; ++i)
        t.u[i] = f2bf(W1[(ks * 32 + lg * 8 + i) * 64 + nt * 16 + lr]);
      fW1[ks][nt] = t.b;
    }
#pragma unroll
  for (int ks = 0; ks < 2; ++ks) {
    union { unsigned short u[8]; bf16x8 b; } t;
#pragma unroll
    for (int i = 0; i < 8; ++i)
      t.u[i] = f2bf(W2[(ks * 32 + lg * 8 + i) * 16 + lr]);
    fW2[ks] = t.b;
  }
#pragma unroll
  for (int nt = 0; nt < 4; ++nt) {
    union { unsigned short u[8]; bf16x8 b; } t;
#pragma unroll
    for (int i = 0; i < 8; ++i) {
      const int k = lg * 8 + i;
      t.u[i] = (k < 18) ? f2bf(Wr1[k * 64 + nt * 16 + lr]) : (unsigned short)0;
    }
    fR1[nt] = t.b;
  }
#pragma unroll
  for (int ks = 0; ks < 2; ++ks) {
    union { unsigned short u[8]; bf16x8 b; } t;
#pragma unroll
    for (int i = 0; i < 8; ++i)
      t.u[i] = (lr < 3) ? f2bf(Wr2[(ks * 32 + lg * 8 + i) * 3 + lr]) : (unsigned short)0;
    fR2[ks] = t.b;
  }
  float b1v[4], br1v[4];
#pragma unroll
  for (int nt = 0; nt < 4; ++nt) { b1v[nt] = b1[nt * 16 + lr]; br1v[nt] = br1[nt * 16 + lr]; }
  const float b2v = b2[lr];
  const float br2v = (lr < 3) ? br2[lr] : 0.f;

  const float foc = 0.5f * (float)RESN / tanf(FOVF * 0.5f);

  for (int chunk = 0; chunk < NCHUNK; ++chunk) {
    __syncthreads();   // prev chunk's GEMM4 hbuf reads + GEMM2-epi dirS reads done
    // ---- setup: 2 threads per sample (128 rows, 256 threads) ----
    const int mc = tid >> 1;
    const int half = tid & 1;
    const int sb = chunk * CH + mc;
    const bool valid = sb < SB;
    float px = 0, py = 0, pz = 0;
    int view = 0;
    if (valid) {
      const int rb = sb / NSAMP;
      const int s = sb - rb * NSAMP;
      const int ray = blockIdx.x * RPB + rb;
      view = ray >> 12;
      const int p = ray & 4095;
      const float dx = ((float)(p & 63) + 0.5f - 32.f) / foc;
      const float dy = ((float)(p >> 6) + 0.5f - 32.f) / foc;
      const float* M = c2w + view * 16;
      const float rdx = M[0] * dx + M[1] * dy + M[2];
      const float rdy = M[4] * dx + M[5] * dy + M[6];
      const float rdz = M[8] * dx + M[9] * dy + M[10];
      const float jit = t_jitter[(size_t)ray * NSAMP + s];
      const float t = 1.0f + ((float)s + jit) * STEPF + STEPF * 0.5f;
      px = fminf(fmaxf(M[3] + 0.5f + rdx * t, 0.f), 1.f);
      py = fminf(fmaxf(M[7] + 0.5f + rdy * t, 0.f), 1.f);
      pz = fminf(fmaxf(M[11] + 0.5f + rdz * t, 0.f), 1.f);
      if (half == 0) {
        uint2 d;
        d.x = (unsigned int)f2bf(rdx) | ((unsigned int)f2bf(rdy) << 16);
        d.y = (unsigned int)f2bf(rdz);
        dirS[mc] = d;
      }
    }

    // ---- GEMM1: feat[128x96] @ W1, K streamed per plane ----
    f32x4 acc1[2][4] = {};
#pragma unroll
    for (int pl = 0; pl < 3; ++pl) {
      if (pl) __syncthreads();           // prev plane A-reads done
      if (valid) {
        const float uu = (pl == 2) ? py : px;
        const float vv = (pl == 0) ? py : pz;
        const float xf = uu * 255.f, yf = vv * 255.f;
        const float x0f = floorf(xf), y0f = floorf(yf);
        const float wx = xf - x0f, wy = yf - y0f;
        const int x0 = (int)x0f, y0 = (int)y0f;
        const int x1 = min(x0 + 1, 255), y1 = min(y0 + 1, 255);
        const float w00 = (1.f - wx) * (1.f - wy), w01 = wx * (1.f - wy);
        const float w10 = (1.f - wx) * wy, w11 = wx * wy;
        bf16x8 v0, v1;
        if (TR) {
          const float* pb = planes + (size_t)(view * 3 + pl) * (PRES * PRES * FEATC) + half * 16;
          const float* p00 = pb + (size_t)(y0 * 256 + x0) * 32;
          const float* p01 = pb + (size_t)(y0 * 256 + x1) * 32;
          const float* p10 = pb + (size_t)(y1 * 256 + x0) * 32;
          const float* p11 = pb + (size_t)(y1 * 256 + x1) * 32;
          f32x2 fp[8];
#pragma unroll
          for (int q = 0; q < 4; ++q) {
            const float4 a = *(const float4*)(p00 + q * 4);
            const float4 b = *(const float4*)(p01 + q * 4);
            const float4 c = *(const float4*)(p10 + q * 4);
            const float4 d = *(const float4*)(p11 + q * 4);
            fp[q * 2 + 0] = mk2(a.x, a.y) * w00 + mk2(b.x, b.y) * w01 +
                            mk2(c.x, c.y) * w10 + mk2(d.x, d.y) * w11;
            fp[q * 2 + 1] = mk2(a.z, a.w) * w00 + mk2(b.z, b.w) * w01 +
                            mk2(c.z, c.w) * w10 + mk2(d.z, d.w) * w11;
          }
#pragma unroll
          for (int i = 0; i < 4; ++i) {
            v0[2 * i] = (__bf16)fp[i][0];       v0[2 * i + 1] = (__bf16)fp[i][1];
            v1[2 * i] = (__bf16)fp[4 + i][0];   v1[2 * i + 1] = (__bf16)fp[4 + i][1];
          }
        } else {
          const float* pb = planes + (size_t)(view * 3 + pl) * (FEATC * PRES * PRES) +
                            (size_t)(half * 16) * (PRES * PRES);
          const int o00 = y0 * 256 + x0, o01 = y0 * 256 + x1;
          const int o10 = y1 * 256 + x0, o11 = y1 * 256 + x1;
          float f[16];
#pragma unroll
          for (int cc = 0; cc < 16; ++cc) {
            const float* pc = pb + (size_t)cc * (PRES * PRES);
            f[cc] = pc[o00] * w00 + pc[o01] * w01 + pc[o10] * w10 + pc[o11] * w11;
          }
#pragma unroll
          for (int i = 0; i < 8; ++i) { v0[i] = (__bf16)f[i]; v1[i] = (__bf16)f[8 + i]; }
        }
        *(bf16x8*)&hbuf[mc][half * 16] = v0;
        *(bf16x8*)&hbuf[mc][half * 16 + 8] = v1;
      }
      __syncthreads();
#pragma unroll
      for (int mt = 0; mt < 2; ++mt) {
        const int m = (2 * w + mt) * 16 + lr;
        const bf16x8 a = *(const bf16x8*)&hbuf[m][lg * 8];
#pragma unroll
        for (int nt = 0; nt < 4; ++nt)
          acc1[mt][nt] = __builtin_amdgcn_mfma_f32_16x16x32_bf16(a, fW1[pl][nt], acc1[mt][nt], 0, 0, 0);
      }
    }
    __syncthreads();
    // h = relu(acc1 + b1) -> hbuf cols 0..63
#pragma unroll
    for (int mt = 0; mt < 2; ++mt)
#pragma unroll
      for (int nt = 0; nt < 4; ++nt)
#pragma unroll
        for (int r = 0; r < 4; ++r) {
          const int m = (2 * w + mt) * 16 + lg * 4 + r;
          hbuf[m][nt * 16 + lr] = (__bf16)fmaxf(acc1[mt][nt][r] + b1v[nt], 0.f);
        }
    __syncthreads();
    // ---- GEMM2: h @ W2 (64->16) ----
    f32x4 acc2[2] = {};
#pragma unroll
    for (int mt = 0; mt < 2; ++mt) {
      const int m = (2 * w + mt) * 16 + lr;
      const bf16x8 a0 = *(const bf16x8*)&hbuf[m][lg * 8];
      const bf16x8 a1 = *(const bf16x8*)&hbuf[m][32 + lg * 8];
      acc2[mt] = __builtin_amdgcn_mfma_f32_16x16x32_bf16(a0, fW2[0], acc2[mt], 0, 0, 0);
      acc2[mt] = __builtin_amdgcn_mfma_f32_16x16x32_bf16(a1, fW2[1], acc2[mt], 0, 0, 0);
    }
    __syncthreads();   // GEMM2 reads done; cols 0..17 now rewritable
    // epilogue: raw sigma -> alphaL; geo -> cols 3..17; dir -> cols 0..2
#pragma unroll
    for (int mt = 0; mt < 2; ++mt)
#pragma unroll
      for (int r = 0; r < 4; ++r) {
        const int m = (2 * w + mt) * 16 + lg * 4 + r;
        const int sb2 = chunk * CH + m;
        const float val = acc2[mt][r] + b2v;
        if (lr == 0) {
          if (sb2 < SB) alphaL[sb2] = val;
          const uint2 d = dirS[m];
          *(unsigned int*)&hbuf[m][0] = d.x;
          *(unsigned short*)&hbuf[m][2] = (unsigned short)d.y;
        } else {
          hbuf[m][2 + lr] = (__bf16)val;   // geo i=lr-1 -> col 3+(lr-1)
        }
      }
    __syncthreads();
    // ---- GEMM3: colorA[128x32] @ Wr1pad (cols 18..31 garbage x zero weights) ----
    f32x4 acc3[2][4] = {};
#pragma unroll
    for (int mt = 0; mt < 2; ++mt) {
      const int m = (2 * w + mt) * 16 + lr;
      const bf16x8 a = *(const bf16x8*)&hbuf[m][lg * 8];
#pragma unroll
      for (int nt = 0; nt < 4; ++nt)
        acc3[mt][nt] = __builtin_amdgcn_mfma_f32_16x16x32_bf16(a, fR1[nt], acc3[mt][nt], 0, 0, 0);
    }
    __syncthreads();   // GEMM3 A-reads done before hr overwrites cols 0..31
#pragma unroll
    for (int mt = 0; mt < 2; ++mt)
#pragma unroll
      for (int nt = 0; nt < 4; ++nt)
#pragma unroll
        for (int r = 0; r < 4; ++r) {
          const int m = (2 * w + mt) * 16 + lg * 4 + r;
          hbuf[m][nt * 16 + lr] = (__bf16)fmaxf(acc3[mt][nt][r] + br1v[nt], 0.f);
        }
    __syncthreads();
    // ---- GEMM4: hr @ Wr2pad -> raw rgb logits ----
    f32x4 acc4[2] = {};
#pragma unroll
    for (int mt = 0; mt < 2; ++mt) {
      const int m = (2 * w + mt) * 16 + lr;
      const bf16x8 a0 = *(const bf16x8*)&hbuf[m][lg * 8];
      const bf16x8 a1 = *(const bf16x8*)&hbuf[m][32 + lg * 8];
      acc4[mt] = __builtin_amdgcn_mfma_f32_16x16x32_bf16(a0, fR2[0], acc4[mt], 0, 0, 0);
      acc4[mt] = __builtin_amdgcn_mfma_f32_16x16x32_bf16(a1, fR2[1], acc4[mt], 0, 0, 0);
    }
#pragma unroll
    for (int mt = 0; mt < 2; ++mt)
#pragma unroll
      for (int r = 0; r < 4; ++r) {
        const int m = (2 * w + mt) * 16 + lg * 4 + r;
        const int sb2 = chunk * CH + m;
        if (lr < 3 && sb2 < SB) rgbL[sb2 * 3 + lr] = acc4[mt][r] + br2v;
      }
  }

  __syncthreads();
  // ---- dense activation phases ----
  for (int i = tid; i < SB; i += TPB) {
    const float v = alphaL[i];
    const float sp = fmaxf(v, 0.f) + log1pf(__expf(-fabsf(v)));
    alphaL[i] = 1.f - __expf(-sp * STEPF);
  }
  for (int i = tid; i < SB * 3; i += TPB) {
    const float x = rgbL[i];
    rgbL[i] = 1.f / (1.f + __expf(-x));
  }
  __syncthreads();

  // ---- wave-parallel composite: wave w -> rays w and w+4 ----
#pragma unroll
  for (int rr = 0; rr < 2; ++rr) {
    const int rloc = w + rr * 4;
    const int ray = blockIdx.x * RPB + rloc;
    const int vw = ray >> 12;
    const int base = rloc * NSAMP;
    // phase A: samples 0..63
    const float a = alphaL[base + lane];
    float q = 1.f - a + 1e-10f;
#pragma unroll
    for (int d = 1; d < 64; d <<= 1) { const float t = __shfl_up(q, d); if (lane >= d) q *= t; }
    float T = __shfl_up(q, 1);
    if (lane == 0) T = 1.f;
    const float wgt = T * a;
    float cr = wgt * rgbL[(base + lane) * 3 + 0];
    float cg = wgt * rgbL[(base + lane) * 3 + 1];
    float cb = wgt * rgbL[(base + lane) * 3 + 2];
    float accA = wgt;
    const float Ttot = __shfl(q, 63);
    // phase B: samples 64..91 on lanes 0..27
    const int i2 = base + 64 + lane;
    const float a2 = (lane < 28) ? alphaL[i2] : 0.f;
    float q2 = 1.f - a2 + 1e-10f;
#pragma unroll
    for (int d = 1; d < 64; d <<= 1) { const float t = __shfl_up(q2, d); if (lane >= d) q2 *= t; }
    float T2 = __shfl_up(q2, 1);
    if (lane == 0) T2 = 1.f;
    T2 *= Ttot;
    if (lane < 28) {
      const float w2 = T2 * a2;
      cr += w2 * rgbL[i2 * 3 + 0];
      cg += w2 * rgbL[i2 * 3 + 1];
      cb += w2 * rgbL[i2 * 3 + 2];
      accA += w2;
    }
#pragma unroll
    for (int d = 32; d; d >>= 1) {
      cr += __shfl_xor(cr, d); cg += __shfl_xor(cg, d);
      cb += __shfl_xor(cb, d); accA += __shfl_xor(accA, d);
    }
    if (lane == 0) {
      const float* bg = background + vw * 3;
      float* po = out + (size_t)ray * 3;
      po[0] = cr + (1.f - accA) * bg[0];
      po[1] = cg + (1.f - accA) * bg[1];
      po[2] = cb + (1.f - accA) * bg[2];
    }
  }
}

extern "C" void kernel_launch(void* const* d_in, const int* in_sizes, int n_in,
                              void* d_out, int out_size, void* d_ws, size_t ws_size,
                              hipStream_t stream) {
  const float* c2w        = (const float*)d_in[0];
  const float* planes     = (const float*)d_in[1];
  const float* background = (const float*)d_in[2];
  const float* t_jitter   = (const float*)d_in[3];
  const float* W1  = (const float*)d_in[4];
  const float* b1  = (const float*)d_in[5];
  const float* W2  = (const float*)d_in[6];
  const float* b2  = (const float*)d_in[7];
  const float* Wr1 = (const float*)d_in[8];
  const float* br1 = (const float*)d_in[9];
  const float* Wr2 = (const float*)d_in[10];
  const float* br2 = (const float*)d_in[11];
  float* out = (float*)d_out;

  const int n_blocks = NVIEWS * PP / RPB;  // 2048
  const size_t tr_bytes = (size_t)NVIEWS * 3 * PRES * PRES * FEATC * sizeof(float);

  if (ws_size >= tr_bytes) {
    float* tp = (float*)d_ws;
    transpose_planes<<<NVIEWS * 3 * PRES, PRES, 0, stream>>>(planes, tp);
    render_mfma<1><<<n_blocks, TPB, 0, stream>>>(
        c2w, tp, background, t_jitter, W1, b1, W2, b2, Wr1, br1, Wr2, br2, out);
  } else {
    render_mfma<0><<<n_blocks, TPB, 0, stream>>>(
        c2w, planes, background, t_jitter, W1, b1, W2, b2, Wr1, br1, Wr2, br2, out);
  }
}